// Round 1
// baseline (225.402 us; speedup 1.0000x reference)
//
#include <hip/hip_runtime.h>

#define NP 81
#define CC 128
#define HH 128
#define WW 256

typedef __attribute__((ext_vector_type(8))) short short8;
typedef __attribute__((ext_vector_type(4))) float f32x4;
typedef __attribute__((ext_vector_type(16))) float f32x16;

__device__ __forceinline__ short f2bf(float f) {
    unsigned int u = __builtin_bit_cast(unsigned int, f);
    u += 0x7fffu + ((u >> 16) & 1u);   // round-to-nearest-even
    return (short)(u >> 16);
}

// Fused cost volume, single kernel (prepass + ws eliminated).
// Block = (b, 32-x strip, 8-y strip), 16 waves x 64 lanes.
// Wave w OWNS t2 row r = y0-4+w: gathers its 16 B-fragments (8 kc x 2 col
// tiles) from fp32 global ONCE, converts to bf16 in registers (64 VGPRs),
// reuses them for every output row y=y0+yy it serves (di = w-yy, yy in
// [max(0,w-8), min(7,w)]). Each (y,di) pair is produced by exactly one wave,
// so there is no cross-wave reduction and only ONE barrier (after t1 staging).
// t1 rows y0..y0+7 live in LDS, XOR-swizzled exactly as the verified
// corr32_v2 ((c/8) ^ (x&15)) for conflict-free b128 writes & reads.
// SIMD balance: waves {w, w+4, w+8, w+12} always total 18 y-iters.
__global__ __launch_bounds__(1024) void corr_fused(
        const float* __restrict__ t1, const float* __restrict__ t2,
        float* __restrict__ out) {
    const int bid = blockIdx.x;
    const int sw  = (bid & 7) * 64 + (bid >> 3);   // XCD-contiguous chunks (512%8==0, bijective)
    const int xt    = sw & 7;
    const int strip = (sw >> 3) & 15;
    const int b     = sw >> 7;
    const int X0 = xt * 32;
    const int y0 = strip * 8;

    const int tid  = threadIdx.x;
    const int lane = tid & 63;
    const int w    = tid >> 6;        // 0..15: owns t2 row y0-4+w
    const int n    = lane & 31;       // MFMA row/col index
    const int g    = lane >> 5;       // k-group

    __shared__ short sA[8 * 32 * 128];        // 64 KB: 8 y-rows of t1, swizzled
    __shared__ float obufs[16 * 9 * 36];      // 20.25 KB: per-wave band buffer

    const size_t plane = (size_t)HH * WW;
    const int r = y0 - 4 + w;                 // t2 row this wave owns

    // ---- B gather: lane holds x' = X0-4+n+32t, c = kc*16 + g*8 + j (bf16x8)
    short8 bre[8][2];
    {
        const bool rok = (r >= 0) && (r < HH);
#pragma unroll
        for (int t = 0; t < 2; ++t) {
            const int x2 = X0 - 4 + n + 32 * t;
            if (rok && x2 >= 0 && x2 < WW) {
                const float* p = t2 + ((size_t)(b * CC + g * 8) * HH + r) * WW + x2;
#pragma unroll
                for (int kc = 0; kc < 8; ++kc) {
                    short8 f;
#pragma unroll
                    for (int j = 0; j < 8; ++j)
                        f[j] = f2bf(p[(size_t)(kc * 16 + j) * plane]);
                    bre[kc][t] = f;
                }
            } else {
#pragma unroll
                for (int kc = 0; kc < 8; ++kc)
                    bre[kc][t] = (short8){0,0,0,0,0,0,0,0};
            }
        }
    }

    // ---- stage A: t1 rows y0..y0+7, 32 x, 128 c (read once, shared by 16 waves)
#pragma unroll
    for (int i = 0; i < 4; ++i) {
        const int unit = tid + i * 1024;            // 4096 units = 8y * 32x * 16oct
        const int x   = unit & 31;
        const int oct = (unit >> 5) & 15;
        const int yy  = unit >> 9;
        const float* p = t1 + ((size_t)(b * CC + oct * 8) * HH + (y0 + yy)) * WW
                       + X0 + x;
        short8 pk;
#pragma unroll
        for (int j = 0; j < 8; ++j) pk[j] = f2bf(p[(size_t)j * plane]);
        *(short8*)&sA[yy * 4096 + x * 128 + ((oct ^ (x & 15)) * 8)] = pk;
    }
    __syncthreads();

    const int ylo = (w > 8) ? (w - 8) : 0;
    const int yhi = (w < 7) ? w : 7;
    float* ob = &obufs[w * 324];                    // [9 dj][36] f32, per wave

    for (int yy = ylo; yy <= yhi; ++yy) {
        const int sbase = yy * 4096 + n * 128;

        // t=0 column tile (acc split t0-then-t1 keeps live VGPRs under the
        // 128-reg cap for 1024-thread blocks)
        f32x16 a0;
#pragma unroll
        for (int q = 0; q < 16; ++q) a0[q] = 0.f;
#pragma unroll
        for (int kc = 0; kc < 8; ++kc) {
            const short8 af = *(const short8*)
                &sA[sbase + (((kc * 2 + g) ^ (n & 15)) * 8)];
            a0 = __builtin_amdgcn_mfma_f32_32x32x16_bf16(af, bre[kc][0], a0, 0, 0, 0);
        }
#pragma unroll
        for (int q = 0; q < 16; ++q) {
            const int m  = (q & 3) + 8 * (q >> 2) + 4 * g;   // D row = x offset
            const int dj = n - m;
            if (dj >= 0 && dj <= 8) ob[dj * 36 + m] = a0[q];
        }

        // t=1 column tile
        f32x16 a1;
#pragma unroll
        for (int q = 0; q < 16; ++q) a1[q] = 0.f;
#pragma unroll
        for (int kc = 0; kc < 8; ++kc) {
            const short8 af = *(const short8*)
                &sA[sbase + (((kc * 2 + g) ^ (n & 15)) * 8)];
            a1 = __builtin_amdgcn_mfma_f32_32x32x16_bf16(af, bre[kc][1], a1, 0, 0, 0);
        }
#pragma unroll
        for (int q = 0; q < 16; ++q) {
            const int m  = (q & 3) + 8 * (q >> 2) + 4 * g;
            const int dj = n - m + 32;
            if (dj >= 0 && dj <= 8) ob[dj * 36 + m] = a1[q];
        }

        // coalesced stores: 9 dj-rows x 32 x as f32x4
        const int di = w - yy;
        const int y  = y0 + yy;
        float* obase = out + ((size_t)(b * NP + di * 9) * HH + y) * WW + X0;
#pragma unroll
        for (int k = 0; k < 2; ++k) {
            const int u = lane + k * 64;
            if (u < 72) {
                const int dj = u >> 3, xq = u & 7;
                f32x4 v = *(const f32x4*)&ob[dj * 36 + xq * 4];
                *(f32x4*)&obase[(size_t)dj * plane + xq * 4] = v;
            }
        }
    }
}

extern "C" void kernel_launch(void* const* d_in, const int* in_sizes, int n_in,
                              void* d_out, int out_size, void* d_ws, size_t ws_size,
                              hipStream_t stream) {
    const float* t1 = (const float*)d_in[0];
    const float* t2 = (const float*)d_in[1];
    corr_fused<<<512, 1024, 0, stream>>>(t1, t2, (float*)d_out);
}

// Round 2
// 224.769 us; speedup vs baseline: 1.0028x; 1.0028x over previous
//
#include <hip/hip_runtime.h>

#define NP 81
#define CC 128
#define HH 128
#define WW 256

typedef __attribute__((ext_vector_type(8))) short short8;
typedef __attribute__((ext_vector_type(4))) float f32x4;
typedef __attribute__((ext_vector_type(16))) float f32x16;

__device__ __forceinline__ short f2bf(float f) {
    unsigned int u = __builtin_bit_cast(unsigned int, f);
    u += 0x7fffu + ((u >> 16) & 1u);   // round-to-nearest-even
    return (short)(u >> 16);
}

// Fused cost volume, single kernel (prepass + ws eliminated).
// Block = (b, 32-x strip, 8-y strip), 16 waves x 64 lanes.
// Wave w OWNS t2 row r = y0-4+w: gathers its 16 B-fragments (8 kc x 2 col
// tiles) from fp32 global ONCE, converts to bf16 in registers (64 VGPRs),
// reuses them for every output row y=y0+yy it serves (di = w-yy).
// Each (y,di) pair is produced by exactly one wave -> no cross-wave
// reduction, ONE barrier (after t1 staging).
//
// R2 fix: __launch_bounds__(1024, 4). A 16-wave block forces 4 waves/EU
// (1 block/CU; LDS 84.5 KB also forces it), which legally allows 128
// VGPRs/thread. Without the second arg the compiler targeted 8 waves/EU
// (64 VGPRs) and SPILLED bre[8][2] to scratch: R1 showed VGPR_Count=64,
// WRITE_SIZE 138 MB (= 42.5 ideal + ~67 MB scratch), MfmaUtil 6%.
__global__ __launch_bounds__(1024, 4) void corr_fused(
        const float* __restrict__ t1, const float* __restrict__ t2,
        float* __restrict__ out) {
    const int bid = blockIdx.x;
    const int sw  = (bid & 7) * 64 + (bid >> 3);   // XCD-contiguous chunks (512%8==0, bijective)
    const int xt    = sw & 7;
    const int strip = (sw >> 3) & 15;
    const int b     = sw >> 7;
    const int X0 = xt * 32;
    const int y0 = strip * 8;

    const int tid  = threadIdx.x;
    const int lane = tid & 63;
    const int w    = tid >> 6;        // 0..15: owns t2 row y0-4+w
    const int n    = lane & 31;       // MFMA row/col index
    const int g    = lane >> 5;       // k-group

    __shared__ short sA[8 * 32 * 128];        // 64 KB: 8 y-rows of t1, swizzled
    __shared__ float obufs[16 * 9 * 36];      // 20.25 KB: per-wave band buffer

    const size_t plane = (size_t)HH * WW;
    const int r = y0 - 4 + w;                 // t2 row this wave owns

    // ---- B gather: lane holds x' = X0-4+n+32t, c = kc*16 + g*8 + j (bf16x8)
    short8 bre[8][2];
    {
        const bool rok = (r >= 0) && (r < HH);
#pragma unroll
        for (int t = 0; t < 2; ++t) {
            const int x2 = X0 - 4 + n + 32 * t;
            if (rok && x2 >= 0 && x2 < WW) {
                const float* p = t2 + ((size_t)(b * CC + g * 8) * HH + r) * WW + x2;
#pragma unroll
                for (int kc = 0; kc < 8; ++kc) {
                    short8 f;
#pragma unroll
                    for (int j = 0; j < 8; ++j)
                        f[j] = f2bf(p[(size_t)(kc * 16 + j) * plane]);
                    bre[kc][t] = f;
                }
            } else {
#pragma unroll
                for (int kc = 0; kc < 8; ++kc)
                    bre[kc][t] = (short8){0,0,0,0,0,0,0,0};
            }
        }
    }

    // ---- stage A: t1 rows y0..y0+7, 32 x, 128 c (read once, shared by 16 waves)
#pragma unroll
    for (int i = 0; i < 4; ++i) {
        const int unit = tid + i * 1024;            // 4096 units = 8y * 32x * 16oct
        const int x   = unit & 31;
        const int oct = (unit >> 5) & 15;
        const int yy  = unit >> 9;
        const float* p = t1 + ((size_t)(b * CC + oct * 8) * HH + (y0 + yy)) * WW
                       + X0 + x;
        short8 pk;
#pragma unroll
        for (int j = 0; j < 8; ++j) pk[j] = f2bf(p[(size_t)j * plane]);
        *(short8*)&sA[yy * 4096 + x * 128 + ((oct ^ (x & 15)) * 8)] = pk;
    }
    __syncthreads();

    const int ylo = (w > 8) ? (w - 8) : 0;
    const int yhi = (w < 7) ? w : 7;
    float* ob = &obufs[w * 324];                    // [9 dj][36] f32, per wave

    for (int yy = ylo; yy <= yhi; ++yy) {
        const int sbase = yy * 4096 + n * 128;

        // t=0 column tile (acc split t0-then-t1 keeps live VGPRs under the
        // 128-reg cap for 1024-thread blocks)
        f32x16 a0;
#pragma unroll
        for (int q = 0; q < 16; ++q) a0[q] = 0.f;
#pragma unroll
        for (int kc = 0; kc < 8; ++kc) {
            const short8 af = *(const short8*)
                &sA[sbase + (((kc * 2 + g) ^ (n & 15)) * 8)];
            a0 = __builtin_amdgcn_mfma_f32_32x32x16_bf16(af, bre[kc][0], a0, 0, 0, 0);
        }
#pragma unroll
        for (int q = 0; q < 16; ++q) {
            const int m  = (q & 3) + 8 * (q >> 2) + 4 * g;   // D row = x offset
            const int dj = n - m;
            if (dj >= 0 && dj <= 8) ob[dj * 36 + m] = a0[q];
        }

        // t=1 column tile
        f32x16 a1;
#pragma unroll
        for (int q = 0; q < 16; ++q) a1[q] = 0.f;
#pragma unroll
        for (int kc = 0; kc < 8; ++kc) {
            const short8 af = *(const short8*)
                &sA[sbase + (((kc * 2 + g) ^ (n & 15)) * 8)];
            a1 = __builtin_amdgcn_mfma_f32_32x32x16_bf16(af, bre[kc][1], a1, 0, 0, 0);
        }
#pragma unroll
        for (int q = 0; q < 16; ++q) {
            const int m  = (q & 3) + 8 * (q >> 2) + 4 * g;
            const int dj = n - m + 32;
            if (dj >= 0 && dj <= 8) ob[dj * 36 + m] = a1[q];
        }

        // coalesced stores: 9 dj-rows x 32 x as f32x4
        const int di = w - yy;
        const int y  = y0 + yy;
        float* obase = out + ((size_t)(b * NP + di * 9) * HH + y) * WW + X0;
#pragma unroll
        for (int k = 0; k < 2; ++k) {
            const int u = lane + k * 64;
            if (u < 72) {
                const int dj = u >> 3, xq = u & 7;
                f32x4 v = *(const f32x4*)&ob[dj * 36 + xq * 4];
                *(f32x4*)&obase[(size_t)dj * plane + xq * 4] = v;
            }
        }
    }
}

extern "C" void kernel_launch(void* const* d_in, const int* in_sizes, int n_in,
                              void* d_out, int out_size, void* d_ws, size_t ws_size,
                              hipStream_t stream) {
    const float* t1 = (const float*)d_in[0];
    const float* t2 = (const float*)d_in[1];
    corr_fused<<<512, 1024, 0, stream>>>(t1, t2, (float*)d_out);
}

// Round 3
// 190.549 us; speedup vs baseline: 1.1829x; 1.1796x over previous
//
#include <hip/hip_runtime.h>

#define NP 81
#define CC 128
#define HH 128
#define WW 256
#define SX 24            // output x-strip width: 24+9-1 = 32 = ONE B tile
#define NXT 11           // ceil(256/24); last strip is 16 wide (predicated)
#define NBLK (NXT * 16 * 4)   // 704 blocks; 704 % 8 == 0 -> bijective XCD swizzle

typedef __attribute__((ext_vector_type(8))) short short8;
typedef __attribute__((ext_vector_type(4))) float f32x4;
typedef __attribute__((ext_vector_type(16))) float f32x16;

__device__ __forceinline__ short f2bf(float f) {
    unsigned int u = __builtin_bit_cast(unsigned int, f);
    u += 0x7fffu + ((u >> 16) & 1u);   // round-to-nearest-even
    return (short)(u >> 16);
}

// Fused cost volume, single kernel. Block = (b, 24-x strip, 8-y strip),
// 16 waves. Wave w owns t2 row r = y0-4+w: gathers ONE 32-wide B-tile
// (x2 = X0-4+n, n=lane&31) as bf16 in registers -- 8 kc x short8 = 32 VGPRs
// (R1/R2 lesson: the 2-tile version needed 64 VGPRs of B and spilled at the
// compiler's 64-reg budget, +95 MB scratch traffic; launch_bounds hints were
// ignored). 24-wide strips make one tile exactly cover the dj band.
// Live regs in main loop ~62 < 64 -> no spill; LDS 63.8 KB -> 2 blocks/CU
// (8 waves/EU, 2x the latency hiding of the 32-wide version).
// Each (y,di) pair is produced by exactly one wave (di = w - yy); band
// extract dj = n - m into per-wave LDS ob, then coalesced f32x4 stores.
// SIMD balance: waves {e,e+4,e+8,e+12} always total 18 yy-iters.
__global__ __launch_bounds__(1024) void corr_fused24(
        const float* __restrict__ t1, const float* __restrict__ t2,
        float* __restrict__ out) {
    const int bid = blockIdx.x;
    const int sw  = (bid & 7) * (NBLK / 8) + (bid >> 3);  // XCD-contiguous
    const int ys = sw & 15;
    const int v  = sw >> 4;          // 0..43
    const int xt = v % NXT;
    const int b  = v / NXT;
    const int X0 = xt * SX;
    const int y0 = ys * 8;

    const int tid  = threadIdx.x;
    const int lane = tid & 63;
    const int w    = tid >> 6;        // 0..15: owns t2 row y0-4+w
    const int n    = lane & 31;       // MFMA A-row m / B-col n index
    const int g    = lane >> 5;       // k-group

    __shared__ short sA[8 * SX * 128];            // 48 KB, XOR-swizzled
    __shared__ __align__(16) float obufs[16 * 9 * 28];  // 15.75 KB

    const size_t plane = (size_t)HH * WW;
    const int r = y0 - 4 + w;                     // t2 row this wave owns

    // ---- B gather: lane holds x2 = X0-4+n, c = kc*16 + g*8 + j (bf16x8)
    short8 bre[8];
    {
        const int x2 = X0 - 4 + n;
        if (r >= 0 && r < HH && x2 >= 0 && x2 < WW) {
            const float* p = t2 + ((size_t)(b * CC + g * 8) * HH + r) * WW + x2;
#pragma unroll
            for (int kc = 0; kc < 8; ++kc) {
                short8 f;
#pragma unroll
                for (int j = 0; j < 8; ++j)
                    f[j] = f2bf(p[(size_t)(kc * 16 + j) * plane]);
                bre[kc] = f;
            }
        } else {
#pragma unroll
            for (int kc = 0; kc < 8; ++kc)
                bre[kc] = (short8){0,0,0,0,0,0,0,0};
        }
    }

    // ---- stage A: t1 rows y0..y0+7, SX x, 128 c (shared by 16 waves)
#pragma unroll
    for (int i = 0; i < 3; ++i) {
        const int unit = tid + i * 1024;          // 3072 = 8y * 24x * 16oct
        const int x    = unit % SX;
        const int rest = unit / SX;               // 0..127
        const int oct  = rest & 15;
        const int yy   = rest >> 4;
        short8 pk = {0,0,0,0,0,0,0,0};
        if (X0 + x < WW) {
            const float* p = t1 + ((size_t)(b * CC + oct * 8) * HH + (y0 + yy)) * WW
                           + X0 + x;
#pragma unroll
            for (int j = 0; j < 8; ++j) pk[j] = f2bf(p[(size_t)j * plane]);
        }
        *(short8*)&sA[yy * (SX * 128) + x * 128 + ((oct ^ (x & 15)) * 8)] = pk;
    }
    __syncthreads();

    const int ylo = (w > 8) ? (w - 8) : 0;
    const int yhi = (w < 7) ? w : 7;
    float* ob = &obufs[w * 252];                  // [9 dj][28] f32, per wave

    for (int yy = ylo; yy <= yhi; ++yy) {
        const int sbase = yy * (SX * 128) + n * 128;

        f32x16 a;
#pragma unroll
        for (int q = 0; q < 16; ++q) a[q] = 0.f;
#pragma unroll
        for (int kc = 0; kc < 8; ++kc) {
            const short8 af = *(const short8*)
                &sA[sbase + (((kc * 2 + g) ^ (n & 15)) * 8)];
            a = __builtin_amdgcn_mfma_f32_32x32x16_bf16(af, bre[kc], a, 0, 0, 0);
        }

        // band extract: D(row m = x offset, col n) -> dj = n - m
#pragma unroll
        for (int q = 0; q < 16; ++q) {
            const int m  = (q & 3) + 8 * (q >> 2) + 4 * g;
            const int dj = n - m;
            if (dj >= 0 && dj <= 8 && m < SX) ob[dj * 28 + m] = a[q];
        }

        // coalesced stores: 9 dj rows x 24 x = 54 f32x4 (one round, lane<54)
        // (same in-wave ob write->read pattern as the verified R1 kernel)
        const int di = w - yy;
        const int y  = y0 + yy;
        if (lane < 54) {
            const int dj = lane / 6, xq = lane % 6;
            if (X0 + xq * 4 < WW) {
                f32x4 vv = *(const f32x4*)&ob[dj * 28 + xq * 4];
                *(f32x4*)&out[((size_t)(b * NP + di * 9 + dj) * HH + y) * WW
                              + X0 + xq * 4] = vv;
            }
        }
    }
}

extern "C" void kernel_launch(void* const* d_in, const int* in_sizes, int n_in,
                              void* d_out, int out_size, void* d_ws, size_t ws_size,
                              hipStream_t stream) {
    const float* t1 = (const float*)d_in[0];
    const float* t2 = (const float*)d_in[1];
    corr_fused24<<<NBLK, 1024, 0, stream>>>(t1, t2, (float*)d_out);
}